// Round 16
// baseline (196.919 us; speedup 1.0000x reference)
//
#include <hip/hip_runtime.h>

typedef unsigned short ushort_t;
typedef __attribute__((ext_vector_type(8)))  short  short8;
typedef __attribute__((ext_vector_type(8)))  ushort_t ushort8;
typedef __attribute__((ext_vector_type(16))) float  f32x16;

#define HWPX 16384
#define EPSV 0.001f

__device__ __forceinline__ ushort_t f2bf(float f) {
    unsigned u = __builtin_bit_cast(unsigned, f);
    unsigned r = u + 0x7FFFu + ((u >> 16) & 1u);   // round-to-nearest-even
    return (ushort_t)(r >> 16);
}

__device__ __forceinline__ unsigned cvt_pk(float a, float b) {
    unsigned r;
    asm("v_cvt_pk_bf16_f32 %0, %1, %2" : "=v"(r) : "v"(a), "v"(b));
    return r;   // lo = bf16(a), hi = bf16(b)
}

__device__ __forceinline__ void gld_lds16(const ushort_t* g, ushort_t* l) {
    __builtin_amdgcn_global_load_lds(
        (const __attribute__((address_space(1))) unsigned int*)g,
        (__attribute__((address_space(3))) unsigned int*)l, 16, 0, 0);
}

// ===================== Pass 1: stats + xb_t + FUSED prep tail ==============
// grid 512 = n(8) x g(8) x q(8); block 512. Main body unchanged (R9 probe:
// at HBM floor). NEW: the 8th-arriving block of each (n,g) (device-scope
// atomic on cnt[n*8+g], canonical threadfence-reduction pattern) runs that
// (n,g)'s reduce + rank-2 cholesky + compose INLINE — prep overlaps the
// stats tail instead of serializing as a 13us 64-block launch (R12 probe).
__device__ __forceinline__ void stats_load(float4 (&buf)[4], const float* xbase,
                                           int w, int col4, int sub) {
    #pragma unroll
    for (int rr = 0; rr < 4; ++rr)
        buf[rr] = *(const float4*)(xbase + (size_t)(w + rr * 8) * HWPX + sub * 256 + col4 * 4);
}

template<bool XBF>
__global__ __launch_bounds__(512, 4) void k_stats(const float* __restrict__ x,
                                                  float* __restrict__ part,
                                                  ushort_t* __restrict__ xbt,
                                                  unsigned* __restrict__ cnt,
                                                  const float* __restrict__ conv_w,
                                                  const float* __restrict__ EK,
                                                  const int* __restrict__ cls_arr,
                                                  ushort_t* __restrict__ M_bf,
                                                  float* __restrict__ bp) {
    __shared__ char smraw[40960];         // union: tile(32KB) | redc(32KB) | prep-scratch
    __shared__ unsigned last;
    ushort_t* tile = (ushort_t*)smraw;    // 2 x (32ch x 256px) bf16, swizzled
    float (*redc)[1024] = (float(*)[1024])smraw;
    float (*redm)[64] = (float(*)[64])(smraw + 32768);
    int b = blockIdx.x;
    int n = b >> 6, g = (b >> 3) & 7, q = b & 7;
    int t = threadIdx.x, w = t >> 6, l = t & 63;
    int lo = l & 31, hi = l >> 5, col4 = l;
    const float* xbase = x + ((size_t)(n * 256 + g * 32)) * HWPX + q * 2048;

    f32x16 acc = {};
    float sm[4] = {0.f, 0.f, 0.f, 0.f};
    float4 buf[4], nxt[4];

    stats_load(buf, xbase, w, col4, 0);
    #pragma unroll 1
    for (int s = 0; s < 8; ++s) {
        if (s < 7) stats_load(nxt, xbase, w, col4, s + 1);
        ushort_t* tl = tile + (s & 1) * 8192;
        #pragma unroll
        for (int rr = 0; rr < 4; ++rr) {
            float4 v = buf[rr];
            sm[rr] += v.x + v.y + v.z + v.w;
            uint2 u;
            u.x = cvt_pk(v.x, v.y);
            u.y = cvt_pk(v.z, v.w);
            int row = w + rr * 8;
            int idx = (row * 256 + col4 * 4) ^ ((row & 7) << 3);   // ushort-idx swizzle
            *(uint2*)&tl[idx] = u;
        }
        asm volatile("s_waitcnt lgkmcnt(0)" ::: "memory");
        __builtin_amdgcn_s_barrier();
        __builtin_amdgcn_sched_barrier(0);
        #pragma unroll
        for (int ks2 = 0; ks2 < 2; ++ks2) {
            int pidx = (lo * 256 + w * 32 + ks2 * 16 + hi * 8) ^ ((lo & 7) << 3);
            short8 f = *(const short8*)&tl[pidx];
            acc = __builtin_amdgcn_mfma_f32_32x32x16_bf16(f, f, acc, 0, 0, 0);
        }
        if (XBF) {
            int pb = q * 64 + s * 8 + w;
            #pragma unroll
            for (int h = 0; h < 2; ++h) {
                ushort8 o;
                #pragma unroll
                for (int j = 0; j < 8; ++j) {
                    int c = h * 16 + hi * 8 + j;
                    o[j] = tl[(c * 256 + w * 32 + lo) ^ ((c & 7) << 3)];
                }
                *(ushort8*)(xbt + ((((size_t)(n * 512 + pb)) * 16 + g * 2 + h) * 64 + l) * 8) = o;
            }
        }
        #pragma unroll
        for (int rr = 0; rr < 4; ++rr) buf[rr] = nxt[rr];
    }

    __syncthreads();
    #pragma unroll
    for (int r = 0; r < 16; ++r) redc[w][l * 16 + r] = acc[r];
    #pragma unroll
    for (int rr = 0; rr < 4; ++rr) redm[w + rr * 8][col4] = sm[rr];
    __syncthreads();

    for (int i = t; i < 1024; i += 512) {
        float v = 0.f;
        #pragma unroll
        for (int ww = 0; ww < 8; ++ww) v += redc[ww][i];
        int ll = i >> 4, r = i & 15;
        int row = (r & 3) + 8 * (r >> 2) + 4 * (ll >> 5);   // C/D layout 32x32 (m74/m101)
        int col = ll & 31;
        part[(size_t)b * 1056 + row * 32 + col] = v;
    }
    if (t < 32) {
        float v = 0.f;
        for (int c = 0; c < 64; ++c) v += redm[t][c];
        part[(size_t)b * 1056 + 1024 + t] = v;
    }

    if (!XBF) return;

    // ---------------- fused prep tail (last block of this (n,g)) ----------
    __syncthreads();
    if (t == 0) {
        __threadfence();                               // release our part stores
        last = atomicAdd(&cnt[(n << 3) + g], 1u);      // device-scope
    }
    __syncthreads();
    if (last != 7u) return;
    __threadfence();                                   // acquire others' part stores

    float* cov2     = (float*)smraw;                   // 4KB (redc is dead)
    float (*A2)[33] = (float(*)[33])(smraw + 4096);    // 4224B
    float* sums2    = (float*)(smraw + 8448);
    float* ml2      = (float*)(smraw + 8576);
    int bg = (n << 3) + g;

    for (int i = t; i < 1024; i += 512) {
        float v = 0.f;
        for (int qq = 0; qq < 8; ++qq) v += part[(size_t)(bg * 8 + qq) * 1056 + i];
        cov2[i] = v;
    }
    if (t < 32) {
        float v = 0.f;
        for (int qq = 0; qq < 8; ++qq) v += part[(size_t)(bg * 8 + qq) * 1056 + 1024 + t];
        sums2[t] = v;
    }
    __syncthreads();

    const float invHW = 1.0f / (float)HWPX;
    #pragma unroll
    for (int p = 0; p < 2; ++p) {
        int idx = t + p * 512;
        int r = idx >> 5, c = idx & 31;
        float mr = sums2[r] * invHW, mc = sums2[c] * invHW;
        A2[r][c] = (cov2[idx] * invHW - mr * mc) * (1.0f - EPSV) + ((r == c) ? EPSV : 0.f);
    }
    if (t < 32) ml2[t] = sums2[t] * invHW;
    __syncthreads();

    // hoisted gather (t<256): loads retire under the chol barrier chain
    int d = t;
    int cls = cls_arr[n];
    float av[32];
    if (t < 256) {
        #pragma unroll
        for (int c = 0; c < 32; ++c)
            av[c] = conv_w[d * 256 + g * 32 + c]
                  + EK[(size_t)cls * 65536 + (size_t)(g * 32 + c) * 256 + d];
    }

    // rank-2 cholesky phases (15 barriers) — identical math to R13 k_prep
    for (int k = 0; k < 30; k += 2) {
        float d0 = A2[k][k];
        float invd0 = 1.0f / d0;
        float r10 = A2[k + 1][k] * invd0;
        float d1 = A2[k + 1][k + 1] - A2[k + 1][k] * r10;
        float invd1 = 1.0f / d1;
        #pragma unroll
        for (int p = 0; p < 2; ++p) {
            int idx = t + p * 512;
            int i = idx >> 5, j = idx & 31;
            if (j > k + 1 && j <= i) {
                float aik = A2[i][k], ajk = A2[j][k];
                float ai1 = A2[i][k + 1] - aik * r10;
                float aj1 = A2[j][k + 1] - ajk * r10;
                A2[i][j] = A2[i][j] - aik * ajk * invd0 - ai1 * aj1 * invd1;
            }
        }
        __syncthreads();
    }
    {   // normalize + final pivot for odd columns (2 barriers)
        float vals[2], dsq[2];
        #pragma unroll
        for (int p = 0; p < 2; ++p) {
            int idx = t + p * 512;
            int i = idx >> 5, j = idx & 31;
            float v, dj;
            if (j & 1) {
                float r = A2[j][j - 1] / A2[j - 1][j - 1];
                dj = A2[j][j] - A2[j][j - 1] * r;
                v  = A2[i][j] - A2[i][j - 1] * r;
            } else {
                dj = A2[j][j];
                v  = A2[i][j];
            }
            vals[p] = v;
            dsq[p] = sqrtf(dj);
        }
        __syncthreads();
        #pragma unroll
        for (int p = 0; p < 2; ++p) {
            int idx = t + p * 512;
            int i = idx >> 5, j = idx & 31;
            if (j <= i) A2[i][j] = vals[p] / dsq[p];
        }
        __syncthreads();
    }

    if (t < 256) {   // compose: solve m·L = a by back-substitution
        float m[32];
        #pragma unroll
        for (int j = 31; j >= 0; --j) {
            float s2 = av[j];
            #pragma unroll
            for (int cp = j + 1; cp < 32; ++cp) s2 -= m[cp] * A2[cp][j];
            m[j] = s2 / A2[j][j];
        }
        float bpv = 0.f;
        ushort8 pk[4];
        #pragma unroll
        for (int cp = 0; cp < 32; ++cp) {
            bpv += m[cp] * ml2[cp];
            pk[cp >> 3][cp & 7] = f2bf(m[cp]);
        }
        #pragma unroll
        for (int kk = 0; kk < 4; ++kk) {
            size_t u = (((size_t)(n * 8 + (d >> 5)) * 16) + g * 2 + (kk >> 1)) * 64
                       + (d & 31) + 32 * (kk & 1);
            *(ushort8*)(M_bf + u * 8) = pk[kk];
        }
        bp[(size_t)bg * 256 + d] = bpv;
    }
}

// ===================== Pass 2 (fallback only): reduce + chol + compose =====
template<bool FRAG>
__global__ __launch_bounds__(256, 1) void k_prep(const float* __restrict__ part,
                                                 const float* __restrict__ conv_w,
                                                 const float* __restrict__ EK,
                                                 const int* __restrict__ cls_arr,
                                                 ushort_t* __restrict__ M_bf,
                                                 float* __restrict__ bp) {
    int bid = blockIdx.x;
    int n = bid >> 3, g = bid & 7;
    int t = threadIdx.x;
    __shared__ float cov[1024];
    __shared__ float sums[32];
    __shared__ float A[32][33];
    __shared__ float ml[32];
    __shared__ float cw[256][33];

    for (int i = 0; i < 8; ++i) {
        int r = i * 32 + (t >> 3);
        float4 v = *(const float4*)(conv_w + r * 256 + g * 32 + (t & 7) * 4);
        #pragma unroll
        for (int e = 0; e < 4; ++e) cw[r][(t & 7) * 4 + e] = ((float*)&v)[e];
    }

    for (int i = t; i < 1024; i += 256) {
        float v = 0.f;
        for (int q = 0; q < 8; ++q) v += part[(size_t)(bid * 8 + q) * 1056 + i];
        cov[i] = v;
    }
    if (t < 32) {
        float v = 0.f;
        for (int q = 0; q < 8; ++q) v += part[(size_t)(bid * 8 + q) * 1056 + 1024 + t];
        sums[t] = v;
    }
    __syncthreads();

    const float invHW = 1.0f / (float)HWPX;
    #pragma unroll
    for (int p = 0; p < 4; ++p) {
        int idx = t + p * 256;
        int r = idx >> 5, c = idx & 31;
        float mr = sums[r] * invHW, mc = sums[c] * invHW;
        A[r][c] = (cov[idx] * invHW - mr * mc) * (1.0f - EPSV) + ((r == c) ? EPSV : 0.f);
    }
    if (t < 32) ml[t] = sums[t] * invHW;
    __syncthreads();

    int d = t;
    int cls = cls_arr[n];
    float a[32];
    #pragma unroll
    for (int c = 0; c < 32; ++c)
        a[c] = cw[d][c] + EK[(size_t)cls * 65536 + (size_t)(g * 32 + c) * 256 + d];

    for (int k = 0; k < 30; k += 2) {
        float d0 = A[k][k];
        float invd0 = 1.0f / d0;
        float r10 = A[k + 1][k] * invd0;
        float d1 = A[k + 1][k + 1] - A[k + 1][k] * r10;
        float invd1 = 1.0f / d1;
        #pragma unroll
        for (int p = 0; p < 4; ++p) {
            int idx = t + p * 256;
            int i = idx >> 5, j = idx & 31;
            if (j > k + 1 && j <= i) {
                float aik = A[i][k], ajk = A[j][k];
                float ai1 = A[i][k + 1] - aik * r10;
                float aj1 = A[j][k + 1] - ajk * r10;
                A[i][j] = A[i][j] - aik * ajk * invd0 - ai1 * aj1 * invd1;
            }
        }
        __syncthreads();
    }
    {
        float vals[4], dsq[4];
        #pragma unroll
        for (int p = 0; p < 4; ++p) {
            int idx = t + p * 256;
            int i = idx >> 5, j = idx & 31;
            float v, dj;
            if (j & 1) {
                float r = A[j][j - 1] / A[j - 1][j - 1];
                dj = A[j][j] - A[j][j - 1] * r;
                v  = A[i][j] - A[i][j - 1] * r;
            } else {
                dj = A[j][j];
                v  = A[i][j];
            }
            vals[p] = v;
            dsq[p] = sqrtf(dj);
        }
        __syncthreads();
        #pragma unroll
        for (int p = 0; p < 4; ++p) {
            int idx = t + p * 256;
            int i = idx >> 5, j = idx & 31;
            if (j <= i) A[i][j] = vals[p] / dsq[p];
        }
        __syncthreads();
    }

    float m[32];
    #pragma unroll
    for (int j = 31; j >= 0; --j) {
        float s = a[j];
        #pragma unroll
        for (int cp = j + 1; cp < 32; ++cp) s -= m[cp] * A[cp][j];
        m[j] = s / A[j][j];
    }

    float bpv = 0.f;
    ushort8 pk[4];
    #pragma unroll
    for (int cp = 0; cp < 32; ++cp) {
        bpv += m[cp] * ml[cp];
        pk[cp >> 3][cp & 7] = f2bf(m[cp]);
    }
    if (FRAG) {
        #pragma unroll
        for (int kk = 0; kk < 4; ++kk) {
            size_t u = (((size_t)(n * 8 + (d >> 5)) * 16) + g * 2 + (kk >> 1)) * 64
                       + (d & 31) + 32 * (kk & 1);
            *(ushort8*)(M_bf + u * 8) = pk[kk];
        }
    } else {
        ushort_t* dst = M_bf + ((size_t)(n * 256 + d)) * 256 + g * 32;
        #pragma unroll
        for (int k = 0; k < 4; ++k) *(ushort8*)(dst + k * 8) = pk[k];
    }
    bp[(size_t)(n * 8 + g) * 256 + d] = bpv;
}

// ===================== Pass 3 (fallback only): bias ========================
__global__ __launch_bounds__(256) void k_bias(const float* __restrict__ conv_b,
                                              const float* __restrict__ EB,
                                              const int* __restrict__ cls_arr,
                                              const float* __restrict__ bp,
                                              float* __restrict__ bias) {
    int n = blockIdx.x, d = threadIdx.x;
    int cls = cls_arr[n];
    float v = conv_b[d] + EB[cls * 256 + d];
    #pragma unroll
    for (int g = 0; g < 8; ++g) v -= bp[(size_t)(n * 8 + g) * 256 + d];
    bias[n * 256 + d] = v;
}

// ===================== Pass 4: out = M_t * xb_t + bias (R14, probe removed) =
// R15 probe verdict: HBM-bound (5.2 TB/s mixed, 65% peak; MFMA 20%, VALU 11%,
// conflicts 0) — ~80% of the realistic mixed R/W ceiling. Structure final.
__global__ __launch_bounds__(512, 4) void k_gemm_s(const ushort_t* __restrict__ xbt,
                                                   const ushort_t* __restrict__ M_t,
                                                   const float* __restrict__ conv_b,
                                                   const float* __restrict__ EB,
                                                   const int* __restrict__ cls_arr,
                                                   const float* __restrict__ bp,
                                                   float* __restrict__ out) {
    __shared__ ushort_t bstage[32768];   // 4 x 16KB
    __shared__ float bias_l[256];
    int bid = blockIdx.x;
    int n = bid >> 6, pt = bid & 63;
    int t = threadIdx.x, w = t >> 6, l = t & 63, lo = l & 31, hi = l >> 5;
    int dblk = w * 32;

    if (t < 256) {
        int cls = cls_arr[n];
        float v = conv_b[t] + EB[cls * 256 + t];
        #pragma unroll
        for (int g = 0; g < 8; ++g) v -= bp[(size_t)(n * 8 + g) * 256 + t];
        bias_l[t] = v;
    }

    const ushort_t* msrc = M_t + (((size_t)(n * 8 + w) * 16) * 64 + l) * 8;
    short8 a[16];
    #pragma unroll
    for (int ks = 0; ks < 16; ++ks)
        a[ks] = *(const short8*)(msrc + (size_t)ks * 512);

    const ushort_t* xsrc = xbt + (size_t)(n * 512 + pt * 8) * 8192;   // 8 pb x 16KB

    #pragma unroll
    for (int p = 0; p < 3; ++p) {
        const ushort_t* src = xsrc + (size_t)p * 8192;
        gld_lds16(src + w * 1024 + l * 8,       bstage + p * 8192 + w * 1024);
        gld_lds16(src + w * 1024 + 512 + l * 8, bstage + p * 8192 + w * 1024 + 512);
    }
    asm volatile("s_waitcnt vmcnt(4) lgkmcnt(0)" ::: "memory");  // gld(0) + bias_l done
    __builtin_amdgcn_s_barrier();
    __builtin_amdgcn_sched_barrier(0);

    float4 bsv4[4];
    #pragma unroll
    for (int qq = 0; qq < 4; ++qq)
        bsv4[qq] = *(const float4*)&bias_l[dblk + 8 * qq + 4 * hi];

    #pragma unroll 1
    for (int pb = 0; pb < 8; ++pb) {
        ushort_t* bufc = bstage + (pb & 3) * 8192;
        if (pb + 3 < 8) {
            ushort_t* bufn = bstage + ((pb + 3) & 3) * 8192;
            const ushort_t* src = xsrc + (size_t)(pb + 3) * 8192;
            gld_lds16(src + w * 1024 + l * 8,       bufn + w * 1024);
            gld_lds16(src + w * 1024 + 512 + l * 8, bufn + w * 1024 + 512);
        }
        __builtin_amdgcn_sched_barrier(0);

        f32x16 acc = {};
        #pragma unroll
        for (int ks = 0; ks < 16; ++ks) {
            short8 bf = *(const short8*)(bufc + ks * 512 + l * 8);
            acc = __builtin_amdgcn_mfma_f32_32x32x16_bf16(a[ks], bf, acc, 0, 0, 0);
        }

        int px = (pt * 8 + pb) * 32 + lo;
        #pragma unroll
        for (int r = 0; r < 16; ++r) {
            int row = dblk + (r & 3) + 8 * (r >> 2) + 4 * hi;
            out[((size_t)(n * 256 + row)) * HWPX + px] =
                acc[r] + ((const float*)&bsv4[r >> 2])[r & 3];
        }

        if (pb < 7) {
            if (pb == 0)      asm volatile("s_waitcnt vmcnt(20)" ::: "memory");
            else if (pb == 1) asm volatile("s_waitcnt vmcnt(36)" ::: "memory");
            else if (pb < 5)  asm volatile("s_waitcnt vmcnt(52)" ::: "memory");
            else if (pb == 5) asm volatile("s_waitcnt vmcnt(50)" ::: "memory");
            else              asm volatile("s_waitcnt vmcnt(48)" ::: "memory");
            __builtin_amdgcn_sched_barrier(0);
            __builtin_amdgcn_s_barrier();
            __builtin_amdgcn_sched_barrier(0);
        }
    }
}

// ===================== Fallback Pass 4: fp32 x, row-major M ================
__global__ __launch_bounds__(512, 2) void k_gemm_fb(const float* __restrict__ x,
                                                    const ushort_t* __restrict__ M_bf,
                                                    const float* __restrict__ bias,
                                                    float* __restrict__ out) {
    int bid = blockIdx.x;
    int n = bid >> 8, pt = bid & 255;
    int px0 = pt * 64;
    int t = threadIdx.x, w = t >> 6, l = t & 63, lo = l & 31, hi = l >> 5;
    int dblk = w * 32;

    const ushort_t* Mrow = M_bf + ((size_t)(n * 256 + dblk + lo)) * 256;
    const float* xn = x + (size_t)n * 256 * HWPX;

    f32x16 acc0 = {}, acc1 = {};
    for (int ks = 0; ks < 16; ++ks) {
        int c0 = ks * 16 + hi * 8;
        short8 afrag = *(const short8*)(Mrow + c0);
        const float* xc = xn + (size_t)c0 * HWPX + px0 + lo;
        short8 f0, f1;
        #pragma unroll
        for (int bb = 0; bb < 8; ++bb) {
            f0[bb] = (short)f2bf(xc[(size_t)bb * HWPX]);
            f1[bb] = (short)f2bf(xc[(size_t)bb * HWPX + 32]);
        }
        acc0 = __builtin_amdgcn_mfma_f32_32x32x16_bf16(afrag, f0, acc0, 0, 0, 0);
        acc1 = __builtin_amdgcn_mfma_f32_32x32x16_bf16(afrag, f1, acc1, 0, 0, 0);
    }

    #pragma unroll
    for (int r = 0; r < 16; ++r) {
        int row = dblk + (r & 3) + 8 * (r >> 2) + 4 * hi;
        float bs = bias[n * 256 + row];
        size_t o = ((size_t)(n * 256 + row)) * HWPX + px0 + lo;
        out[o] = acc0[r] + bs;
        out[o + 32] = acc1[r] + bs;
    }
}

// ===========================================================================
extern "C" void kernel_launch(void* const* d_in, const int* in_sizes, int n_in,
                              void* d_out, int out_size, void* d_ws, size_t ws_size,
                              hipStream_t stream) {
    const float* x      = (const float*)d_in[0];
    const int*   cls    = (const int*)d_in[1];
    const float* EK     = (const float*)d_in[2];
    const float* EB     = (const float*)d_in[3];
    const float* conv_w = (const float*)d_in[4];
    const float* conv_b = (const float*)d_in[5];
    float* out = (float*)d_out;

    float* wsf      = (float*)d_ws;
    float* part     = wsf;                          // 512*1056 = 540672 f
    float* bp       = wsf + 540672;                 // 16384 f
    float* bias     = wsf + 557056;                 // 2048 f  (fallback only)
    unsigned* cnt   = (unsigned*)(wsf + 559104);    // 64 u32 (zeroed per call)
    ushort_t* M     = (ushort_t*)(wsf + 559168);    // 8*256*256 bf16 = 1 MiB

    const size_t xb_off   = 559168 * sizeof(float) + (size_t)8 * 256 * 256 * 2; // 3285248
    const size_t xb_bytes = (size_t)8 * HWPX * 256 * 2;                         // 64 MiB
    bool fast = ws_size >= xb_off + xb_bytes;
    ushort_t* xb = (ushort_t*)((char*)d_ws + xb_off);

    if (fast) {
        hipMemsetAsync(cnt, 0, 64 * sizeof(unsigned), stream);   // per-call, graph-safe
        k_stats<true>  <<<512, 512, 0, stream>>>(x, part, xb, cnt,
                                                 conv_w, EK, cls, M, bp);
        k_gemm_s       <<<512, 512, 0, stream>>>(xb, M, conv_b, EB, cls, bp, out);
    } else {
        k_stats<false> <<<512, 512, 0, stream>>>(x, part, M, nullptr,
                                                 conv_w, EK, cls, M, bp);
        k_prep<false>  <<<64,  256, 0, stream>>>(part, conv_w, EK, cls, M, bp);
        k_bias         <<<8,   256, 0, stream>>>(conv_b, EB, cls, bp, bias);
        k_gemm_fb      <<<2048, 512, 0, stream>>>(x, M, bias, out);
    }
}

// Round 17
// 87.964 us; speedup vs baseline: 2.2386x; 2.2386x over previous
//
#include <hip/hip_runtime.h>

typedef unsigned short ushort_t;
typedef __attribute__((ext_vector_type(8)))  short  short8;
typedef __attribute__((ext_vector_type(8)))  ushort_t ushort8;
typedef __attribute__((ext_vector_type(16))) float  f32x16;

#define HWPX 16384
#define EPSV 0.001f

__device__ __forceinline__ ushort_t f2bf(float f) {
    unsigned u = __builtin_bit_cast(unsigned, f);
    unsigned r = u + 0x7FFFu + ((u >> 16) & 1u);   // round-to-nearest-even
    return (ushort_t)(r >> 16);
}

__device__ __forceinline__ unsigned cvt_pk(float a, float b) {
    unsigned r;
    asm("v_cvt_pk_bf16_f32 %0, %1, %2" : "=v"(r) : "v"(a), "v"(b));
    return r;   // lo = bf16(a), hi = bf16(b)
}

__device__ __forceinline__ void gld_lds16(const ushort_t* g, ushort_t* l) {
    __builtin_amdgcn_global_load_lds(
        (const __attribute__((address_space(1))) unsigned int*)g,
        (__attribute__((address_space(3))) unsigned int*)l, 16, 0, 0);
}

// ===================== Pass 1: coalesced stats + frag-ordered xb_t =========
// REVERTED to R14 (R16's fused prep-tail spilled the main loop to scratch:
// 190us, VALUBusy 3% — rule-#20 via worst-path register pressure).
// R9 probe: ~26us warm / ~31us cold = at its HBM read+write floor.
__device__ __forceinline__ void stats_load(float4 (&buf)[4], const float* xbase,
                                           int w, int col4, int sub) {
    #pragma unroll
    for (int rr = 0; rr < 4; ++rr)
        buf[rr] = *(const float4*)(xbase + (size_t)(w + rr * 8) * HWPX + sub * 256 + col4 * 4);
}

template<bool XBF>
__global__ __launch_bounds__(512, 4) void k_stats(const float* __restrict__ x,
                                                  float* __restrict__ part,
                                                  ushort_t* __restrict__ xbt) {
    __shared__ char smraw[40960];         // union: tile(32KB) | redc(32KB); +redm 8KB
    ushort_t* tile = (ushort_t*)smraw;    // 2 x (32ch x 256px) bf16, swizzled
    float (*redc)[1024] = (float(*)[1024])smraw;
    float (*redm)[64] = (float(*)[64])(smraw + 32768);
    int b = blockIdx.x;
    int n = b >> 6, g = (b >> 3) & 7, q = b & 7;
    int t = threadIdx.x, w = t >> 6, l = t & 63;
    int lo = l & 31, hi = l >> 5, col4 = l;
    const float* xbase = x + ((size_t)(n * 256 + g * 32)) * HWPX + q * 2048;

    f32x16 acc = {};
    float sm[4] = {0.f, 0.f, 0.f, 0.f};
    float4 buf[4], nxt[4];

    stats_load(buf, xbase, w, col4, 0);
    #pragma unroll 1
    for (int s = 0; s < 8; ++s) {
        if (s < 7) stats_load(nxt, xbase, w, col4, s + 1);
        ushort_t* tl = tile + (s & 1) * 8192;
        #pragma unroll
        for (int rr = 0; rr < 4; ++rr) {
            float4 v = buf[rr];
            sm[rr] += v.x + v.y + v.z + v.w;
            uint2 u;
            u.x = cvt_pk(v.x, v.y);
            u.y = cvt_pk(v.z, v.w);
            int row = w + rr * 8;
            int idx = (row * 256 + col4 * 4) ^ ((row & 7) << 3);   // ushort-idx swizzle
            *(uint2*)&tl[idx] = u;
        }
        asm volatile("s_waitcnt lgkmcnt(0)" ::: "memory");
        __builtin_amdgcn_s_barrier();
        __builtin_amdgcn_sched_barrier(0);
        #pragma unroll
        for (int ks2 = 0; ks2 < 2; ++ks2) {
            int pidx = (lo * 256 + w * 32 + ks2 * 16 + hi * 8) ^ ((lo & 7) << 3);
            short8 f = *(const short8*)&tl[pidx];
            acc = __builtin_amdgcn_mfma_f32_32x32x16_bf16(f, f, acc, 0, 0, 0);
        }
        if (XBF) {
            int pb = q * 64 + s * 8 + w;
            #pragma unroll
            for (int h = 0; h < 2; ++h) {
                ushort8 o;
                #pragma unroll
                for (int j = 0; j < 8; ++j) {
                    int c = h * 16 + hi * 8 + j;
                    o[j] = tl[(c * 256 + w * 32 + lo) ^ ((c & 7) << 3)];
                }
                *(ushort8*)(xbt + ((((size_t)(n * 512 + pb)) * 16 + g * 2 + h) * 64 + l) * 8) = o;
            }
        }
        #pragma unroll
        for (int rr = 0; rr < 4; ++rr) buf[rr] = nxt[rr];
    }

    __syncthreads();
    #pragma unroll
    for (int r = 0; r < 16; ++r) redc[w][l * 16 + r] = acc[r];
    #pragma unroll
    for (int rr = 0; rr < 4; ++rr) redm[w + rr * 8][col4] = sm[rr];
    __syncthreads();

    for (int i = t; i < 1024; i += 512) {
        float v = 0.f;
        #pragma unroll
        for (int ww = 0; ww < 8; ++ww) v += redc[ww][i];
        int ll = i >> 4, r = i & 15;
        int row = (r & 3) + 8 * (r >> 2) + 4 * (ll >> 5);   // C/D layout 32x32 (m74/m101)
        int col = ll & 31;
        part[(size_t)b * 1056 + row * 32 + col] = v;
    }
    if (t < 32) {
        float v = 0.f;
        for (int c = 0; c < 64; ++c) v += redm[t][c];
        part[(size_t)b * 1056 + 1024 + t] = v;
    }
}

// ===================== Pass 2: reduce + rank-2 LDS chol + compose ==========
// (R13 version — measured P~13-17us, mostly intrinsic barrier/serial chain)
template<bool FRAG>
__global__ __launch_bounds__(256, 1) void k_prep(const float* __restrict__ part,
                                                 const float* __restrict__ conv_w,
                                                 const float* __restrict__ EK,
                                                 const int* __restrict__ cls_arr,
                                                 ushort_t* __restrict__ M_bf,
                                                 float* __restrict__ bp) {
    int bid = blockIdx.x;
    int n = bid >> 3, g = bid & 7;
    int t = threadIdx.x;
    __shared__ float cov[1024];
    __shared__ float sums[32];
    __shared__ float A[32][33];
    __shared__ float ml[32];
    __shared__ float cw[256][33];

    for (int i = 0; i < 8; ++i) {
        int r = i * 32 + (t >> 3);
        float4 v = *(const float4*)(conv_w + r * 256 + g * 32 + (t & 7) * 4);
        #pragma unroll
        for (int e = 0; e < 4; ++e) cw[r][(t & 7) * 4 + e] = ((float*)&v)[e];
    }

    for (int i = t; i < 1024; i += 256) {
        float v = 0.f;
        for (int q = 0; q < 8; ++q) v += part[(size_t)(bid * 8 + q) * 1056 + i];
        cov[i] = v;
    }
    if (t < 32) {
        float v = 0.f;
        for (int q = 0; q < 8; ++q) v += part[(size_t)(bid * 8 + q) * 1056 + 1024 + t];
        sums[t] = v;
    }
    __syncthreads();

    const float invHW = 1.0f / (float)HWPX;
    #pragma unroll
    for (int p = 0; p < 4; ++p) {
        int idx = t + p * 256;
        int r = idx >> 5, c = idx & 31;
        float mr = sums[r] * invHW, mc = sums[c] * invHW;
        A[r][c] = (cov[idx] * invHW - mr * mc) * (1.0f - EPSV) + ((r == c) ? EPSV : 0.f);
    }
    if (t < 32) ml[t] = sums[t] * invHW;
    __syncthreads();

    int d = t;
    int cls = cls_arr[n];
    float a[32];
    #pragma unroll
    for (int c = 0; c < 32; ++c)
        a[c] = cw[d][c] + EK[(size_t)cls * 65536 + (size_t)(g * 32 + c) * 256 + d];

    for (int k = 0; k < 30; k += 2) {
        float d0 = A[k][k];
        float invd0 = 1.0f / d0;
        float r10 = A[k + 1][k] * invd0;
        float d1 = A[k + 1][k + 1] - A[k + 1][k] * r10;
        float invd1 = 1.0f / d1;
        #pragma unroll
        for (int p = 0; p < 4; ++p) {
            int idx = t + p * 256;
            int i = idx >> 5, j = idx & 31;
            if (j > k + 1 && j <= i) {
                float aik = A[i][k], ajk = A[j][k];
                float ai1 = A[i][k + 1] - aik * r10;
                float aj1 = A[j][k + 1] - ajk * r10;
                A[i][j] = A[i][j] - aik * ajk * invd0 - ai1 * aj1 * invd1;
            }
        }
        __syncthreads();
    }
    {
        float vals[4], dsq[4];
        #pragma unroll
        for (int p = 0; p < 4; ++p) {
            int idx = t + p * 256;
            int i = idx >> 5, j = idx & 31;
            float v, dj;
            if (j & 1) {
                float r = A[j][j - 1] / A[j - 1][j - 1];
                dj = A[j][j] - A[j][j - 1] * r;
                v  = A[i][j] - A[i][j - 1] * r;
            } else {
                dj = A[j][j];
                v  = A[i][j];
            }
            vals[p] = v;
            dsq[p] = sqrtf(dj);
        }
        __syncthreads();
        #pragma unroll
        for (int p = 0; p < 4; ++p) {
            int idx = t + p * 256;
            int i = idx >> 5, j = idx & 31;
            if (j <= i) A[i][j] = vals[p] / dsq[p];
        }
        __syncthreads();
    }

    float m[32];
    #pragma unroll
    for (int j = 31; j >= 0; --j) {
        float s = a[j];
        #pragma unroll
        for (int cp = j + 1; cp < 32; ++cp) s -= m[cp] * A[cp][j];
        m[j] = s / A[j][j];
    }

    float bpv = 0.f;
    ushort8 pk[4];
    #pragma unroll
    for (int cp = 0; cp < 32; ++cp) {
        bpv += m[cp] * ml[cp];
        pk[cp >> 3][cp & 7] = f2bf(m[cp]);
    }
    if (FRAG) {
        #pragma unroll
        for (int kk = 0; kk < 4; ++kk) {
            size_t u = (((size_t)(n * 8 + (d >> 5)) * 16) + g * 2 + (kk >> 1)) * 64
                       + (d & 31) + 32 * (kk & 1);
            *(ushort8*)(M_bf + u * 8) = pk[kk];
        }
    } else {
        ushort_t* dst = M_bf + ((size_t)(n * 256 + d)) * 256 + g * 32;
        #pragma unroll
        for (int k = 0; k < 4; ++k) *(ushort8*)(dst + k * 8) = pk[k];
    }
    bp[(size_t)(n * 8 + g) * 256 + d] = bpv;
}

// ===================== Pass 3 (fallback only): bias ========================
__global__ __launch_bounds__(256) void k_bias(const float* __restrict__ conv_b,
                                              const float* __restrict__ EB,
                                              const int* __restrict__ cls_arr,
                                              const float* __restrict__ bp,
                                              float* __restrict__ bias) {
    int n = blockIdx.x, d = threadIdx.x;
    int cls = cls_arr[n];
    float v = conv_b[d] + EB[cls * 256 + d];
    #pragma unroll
    for (int g = 0; g < 8; ++g) v -= bp[(size_t)(n * 8 + g) * 256 + d];
    bias[n * 256 + d] = v;
}

// ===================== Pass 4: out = M_t * xb_t + bias =====================
// R14 structure (R15 probe: HBM-bound, 5.2 TB/s mixed, conflicts 0, no spill).
// NEW: out stores are NON-TEMPORAL (nt) — out is a 131MB pure write stream
// never re-read; nt skips write-allocate/L2-dirty overhead.
__global__ __launch_bounds__(512, 4) void k_gemm_s(const ushort_t* __restrict__ xbt,
                                                   const ushort_t* __restrict__ M_t,
                                                   const float* __restrict__ conv_b,
                                                   const float* __restrict__ EB,
                                                   const int* __restrict__ cls_arr,
                                                   const float* __restrict__ bp,
                                                   float* __restrict__ out) {
    __shared__ ushort_t bstage[32768];   // 4 x 16KB
    __shared__ float bias_l[256];
    int bid = blockIdx.x;
    int n = bid >> 6, pt = bid & 63;
    int t = threadIdx.x, w = t >> 6, l = t & 63, lo = l & 31, hi = l >> 5;
    int dblk = w * 32;

    if (t < 256) {
        int cls = cls_arr[n];
        float v = conv_b[t] + EB[cls * 256 + t];
        #pragma unroll
        for (int g = 0; g < 8; ++g) v -= bp[(size_t)(n * 8 + g) * 256 + t];
        bias_l[t] = v;
    }

    const ushort_t* msrc = M_t + (((size_t)(n * 8 + w) * 16) * 64 + l) * 8;
    short8 a[16];
    #pragma unroll
    for (int ks = 0; ks < 16; ++ks)
        a[ks] = *(const short8*)(msrc + (size_t)ks * 512);

    const ushort_t* xsrc = xbt + (size_t)(n * 512 + pt * 8) * 8192;   // 8 pb x 16KB

    #pragma unroll
    for (int p = 0; p < 3; ++p) {
        const ushort_t* src = xsrc + (size_t)p * 8192;
        gld_lds16(src + w * 1024 + l * 8,       bstage + p * 8192 + w * 1024);
        gld_lds16(src + w * 1024 + 512 + l * 8, bstage + p * 8192 + w * 1024 + 512);
    }
    asm volatile("s_waitcnt vmcnt(4) lgkmcnt(0)" ::: "memory");  // gld(0) + bias_l done
    __builtin_amdgcn_s_barrier();
    __builtin_amdgcn_sched_barrier(0);

    float4 bsv4[4];
    #pragma unroll
    for (int qq = 0; qq < 4; ++qq)
        bsv4[qq] = *(const float4*)&bias_l[dblk + 8 * qq + 4 * hi];

    #pragma unroll 1
    for (int pb = 0; pb < 8; ++pb) {
        ushort_t* bufc = bstage + (pb & 3) * 8192;
        if (pb + 3 < 8) {
            ushort_t* bufn = bstage + ((pb + 3) & 3) * 8192;
            const ushort_t* src = xsrc + (size_t)(pb + 3) * 8192;
            gld_lds16(src + w * 1024 + l * 8,       bufn + w * 1024);
            gld_lds16(src + w * 1024 + 512 + l * 8, bufn + w * 1024 + 512);
        }
        __builtin_amdgcn_sched_barrier(0);

        f32x16 acc = {};
        #pragma unroll
        for (int ks = 0; ks < 16; ++ks) {
            short8 bf = *(const short8*)(bufc + ks * 512 + l * 8);
            acc = __builtin_amdgcn_mfma_f32_32x32x16_bf16(a[ks], bf, acc, 0, 0, 0);
        }

        int px = (pt * 8 + pb) * 32 + lo;
        #pragma unroll
        for (int r = 0; r < 16; ++r) {
            int row = dblk + (r & 3) + 8 * (r >> 2) + 4 * hi;
            __builtin_nontemporal_store(
                acc[r] + ((const float*)&bsv4[r >> 2])[r & 3],
                &out[((size_t)(n * 256 + row)) * HWPX + px]);
        }

        if (pb < 7) {
            if (pb == 0)      asm volatile("s_waitcnt vmcnt(20)" ::: "memory");
            else if (pb == 1) asm volatile("s_waitcnt vmcnt(36)" ::: "memory");
            else if (pb < 5)  asm volatile("s_waitcnt vmcnt(52)" ::: "memory");
            else if (pb == 5) asm volatile("s_waitcnt vmcnt(50)" ::: "memory");
            else              asm volatile("s_waitcnt vmcnt(48)" ::: "memory");
            __builtin_amdgcn_sched_barrier(0);
            __builtin_amdgcn_s_barrier();
            __builtin_amdgcn_sched_barrier(0);
        }
    }
}

// ===================== Fallback Pass 4: fp32 x, row-major M ================
__global__ __launch_bounds__(512, 2) void k_gemm_fb(const float* __restrict__ x,
                                                    const ushort_t* __restrict__ M_bf,
                                                    const float* __restrict__ bias,
                                                    float* __restrict__ out) {
    int bid = blockIdx.x;
    int n = bid >> 8, pt = bid & 255;
    int px0 = pt * 64;
    int t = threadIdx.x, w = t >> 6, l = t & 63, lo = l & 31, hi = l >> 5;
    int dblk = w * 32;

    const ushort_t* Mrow = M_bf + ((size_t)(n * 256 + dblk + lo)) * 256;
    const float* xn = x + (size_t)n * 256 * HWPX;

    f32x16 acc0 = {}, acc1 = {};
    for (int ks = 0; ks < 16; ++ks) {
        int c0 = ks * 16 + hi * 8;
        short8 afrag = *(const short8*)(Mrow + c0);
        const float* xc = xn + (size_t)c0 * HWPX + px0 + lo;
        short8 f0, f1;
        #pragma unroll
        for (int bb = 0; bb < 8; ++bb) {
            f0[bb] = (short)f2bf(xc[(size_t)bb * HWPX]);
            f1[bb] = (short)f2bf(xc[(size_t)bb * HWPX + 32]);
        }
        acc0 = __builtin_amdgcn_mfma_f32_32x32x16_bf16(afrag, f0, acc0, 0, 0, 0);
        acc1 = __builtin_amdgcn_mfma_f32_32x32x16_bf16(afrag, f1, acc1, 0, 0, 0);
    }

    #pragma unroll
    for (int r = 0; r < 16; ++r) {
        int row = dblk + (r & 3) + 8 * (r >> 2) + 4 * hi;
        float bs = bias[n * 256 + row];
        size_t o = ((size_t)(n * 256 + row)) * HWPX + px0 + lo;
        out[o] = acc0[r] + bs;
        out[o + 32] = acc1[r] + bs;
    }
}

// ===========================================================================
extern "C" void kernel_launch(void* const* d_in, const int* in_sizes, int n_in,
                              void* d_out, int out_size, void* d_ws, size_t ws_size,
                              hipStream_t stream) {
    const float* x      = (const float*)d_in[0];
    const int*   cls    = (const int*)d_in[1];
    const float* EK     = (const float*)d_in[2];
    const float* EB     = (const float*)d_in[3];
    const float* conv_w = (const float*)d_in[4];
    const float* conv_b = (const float*)d_in[5];
    float* out = (float*)d_out;

    float* wsf   = (float*)d_ws;
    float* part  = wsf;                          // 512*1056 = 540672 f
    float* bp    = wsf + 540672;                 // 16384 f
    float* bias  = wsf + 557056;                 // 2048 f  (fallback only)
    ushort_t* M  = (ushort_t*)(wsf + 559104);    // 8*256*256 bf16 = 1 MiB

    const size_t xb_off   = 559104 * sizeof(float) + (size_t)8 * 256 * 256 * 2; // 3284992
    const size_t xb_bytes = (size_t)8 * HWPX * 256 * 2;                         // 64 MiB
    bool fast = ws_size >= xb_off + xb_bytes;
    ushort_t* xb = (ushort_t*)((char*)d_ws + xb_off);

    if (fast) {
        k_stats<true>  <<<512, 512, 0, stream>>>(x, part, xb);
        k_prep<true>   <<<64,  256, 0, stream>>>(part, conv_w, EK, cls, M, bp);
        k_gemm_s       <<<512, 512, 0, stream>>>(xb, M, conv_b, EB, cls, bp, out);
    } else {
        k_stats<false> <<<512, 512, 0, stream>>>(x, part, M);
        k_prep<false>  <<<64,  256, 0, stream>>>(part, conv_w, EK, cls, M, bp);
        k_bias         <<<8,   256, 0, stream>>>(conv_b, EB, cls, bp, bias);
        k_gemm_fb      <<<2048, 512, 0, stream>>>(x, M, bias, out);
    }
}